// Round 6
// baseline (152.396 us; speedup 1.0000x reference)
//
#include <hip/hip_runtime.h>
#include <hip/hip_bf16.h>

// CapsuleLayer routing, bf16 MFMA, 6 dispatches.
// B=512,P=1152,N=10,T=16,D=8, 3 iters. Verified 16x16x32 bf16 layouts:
//   A: m=lane&15, k=q*8+j   B: n=lane&15, k=q*8+j   D: col=lane&15, row=q*4+r
// r19 = r18 + NONTEMPORAL stores on all cross-dispatch staging writes.
// Theory: staging buffers are written by blocks scattered over all 8 XCDs and
// read next dispatch from OTHER XCDs -> dirty remote-L2 lines (~3TB/s probe+
// fabric path). nt stores stream to L3 so readers fetch clean (~12TB/s).
// bbar stays cached: same blockIdx -> same XCD across ga dispatches.
// History: r15 traffic cut -18.6us (L2/L3-bound confirmed); r16 grid-halving
// REGRESSED +10us (coverage matters); r17 XCD swizzle regressed (natural
// mblk%8 mapping already L2-optimal); r18 tail/prep fixes -4.5us;
// r14 TLP/LDS-pad neutral; r11 grid-sync 4x.

typedef __attribute__((ext_vector_type(8))) short bfrag;   // 8 bf16
typedef __attribute__((ext_vector_type(4))) float f32x4;

constexpr int B_ = 512, P_ = 1152, N_ = 10, NT_ = 160;
constexpr int K1_ = 9216, NKC_ = 288;

__device__ __forceinline__ unsigned short f2bf(float f) {
    unsigned u = __float_as_uint(f);
    return (unsigned short)((u + 0x7fffu + ((u >> 16) & 1u)) >> 16);  // RNE
}
__device__ __forceinline__ float bf2f(unsigned short s) {
    return __uint_as_float((unsigned)s << 16);
}
__device__ __forceinline__ bfrag mkfrag(f32x4 a, f32x4 b, float c) {
    bfrag f;
    f[0] = (short)f2bf(a.x * c); f[1] = (short)f2bf(a.y * c);
    f[2] = (short)f2bf(a.z * c); f[3] = (short)f2bf(a.w * c);
    f[4] = (short)f2bf(b.x * c); f[5] = (short)f2bf(b.y * c);
    f[6] = (short)f2bf(b.z * c); f[7] = (short)f2bf(b.w * c);
    return f;
}

// Xb:  [mblk 32][kc 288][lane 64][8]  elem = x[mblk*16+col][kc*32+q*8+j]
// Xga: [pdblk 576][kc 16][lane 64][8] elem = x[kc*32+q*8+j][pdblk*16+col]
// Wc:  [n 10][kc 288][lane 64][8]     elem = c[p,n]*W[p][n*16+col][j], p=kc*4+q
// Wb:  [pdblk 576][lane 64][40]       elem(mt*4+r) = W[p][mt*16+q*4+r][d]
// Vt:  [kc 16][mt 10][lane 64][8]     elem = v[kc*32+q*8+j][mt*16+col]  (bf16)
__global__ __launch_bounds__(256) void k_prep(const float* __restrict__ x,
                                              const float* __restrict__ W,
                                              unsigned short* __restrict__ Xb,
                                              unsigned short* __restrict__ Xga,
                                              unsigned short* __restrict__ Wc,
                                              unsigned short* __restrict__ Wb) {
    __shared__ float smem[5760];   // 23 KB: fused-W stage OR x-transpose tile
    const int bid = blockIdx.x, tid = threadIdx.x;
    const int w = tid >> 6, ln = tid & 63, col = ln & 15, q = ln >> 4;
    if (bid < 288) {           // fused W branch: 4 p's per block, W read once
        const int pb = bid;            // == kc for Wc0
        const int p0 = pb * 4;
        // stage W[p0..p0+3] (5120 floats) coalesced -> LDS stride-9 pad
#pragma unroll
        for (int k = 0; k < 20; ++k) {
            const int e = k * 256 + tid;          // [0,5120)
            const int pl = e / 1280, rem = e % 1280;
            const int row = rem >> 3, d = rem & 7;
            smem[pl * 1440 + row * 9 + d] = W[(size_t)p0 * 1280 + e];
        }
        __syncthreads();
        // Wc0 = bf16(0.1*W): 10 (n) tasks over 4 waves; p = p0 + q
        for (int n = w; n < N_; n += 4) {
            const float* src = smem + q * 1440 + (n * 16 + col) * 9;
            bfrag f;
#pragma unroll
            for (int j = 0; j < 8; ++j) f[j] = (short)f2bf(src[j] * 0.1f);
            __builtin_nontemporal_store(f,
                (bfrag*)(Wc + ((size_t)(n * NKC_ + pb)) * 512 + ln * 8));
        }
        // Wb: this block covers pdblk 2*pb + {0,1}; threads 0..127 emit
        if (tid < 128) {
            const int pdblk_l = tid >> 6;          // 0..1
            const int lane = tid & 63, c2 = lane & 15, q2 = lane >> 4;
            const int p_l = (pdblk_l * 16 + c2) >> 3, d = c2 & 7;
            const float* src = smem + p_l * 1440 + d;
            unsigned short* dst = Wb + ((size_t)((2 * pb + pdblk_l) * 64 + lane)) * 40;
#pragma unroll
            for (int mt = 0; mt < N_; ++mt)
#pragma unroll
                for (int r = 0; r < 4; ++r)
                    __builtin_nontemporal_store(
                        f2bf(src[(mt * 16 + q2 * 4 + r) * 9]), dst + mt * 4 + r);
        }
    } else {                   // x transpose tile -> Xga AND Xb fragments
        unsigned short (*tile)[72] = (unsigned short (*)[72])smem;  // 64x72
        const int tb = bid - 288;
        const int pd0 = (tb >> 3) * 64, b0 = (tb & 7) * 64;
        const int c0 = tid & 63, r0 = tid >> 6;
#pragma unroll
        for (int i = 0; i < 16; ++i) {
            const int br = i * 4 + r0;   // coalesced: 64 lanes x 4B contiguous
            tile[c0][br] = f2bf(x[(size_t)(b0 + br) * K1_ + pd0 + c0]);
        }
        __syncthreads();
        // Xga: 8 frags (pdblk_l 0..3, kc_l 0..1); wave w does f=w, f=w+4
#pragma unroll
        for (int fi = 0; fi < 2; ++fi) {
            const int f = w + fi * 4;
            const int pdblk_l = f & 3, kc_l = f >> 2;
            bfrag fr;
#pragma unroll
            for (int j = 0; j < 8; ++j)
                fr[j] = (short)tile[pdblk_l * 16 + col][kc_l * 32 + q * 8 + j];
            const size_t addr = ((size_t)(((pd0 >> 4) + pdblk_l) * 16 + (b0 >> 5) + kc_l)) * 512 + ln * 8;
            __builtin_nontemporal_store(fr, (bfrag*)(Xga + addr));
        }
        // Xb: 8 frags (mblk_l 0..3, kc_l 0..1); wave w does f=w, f=w+4
#pragma unroll
        for (int fi = 0; fi < 2; ++fi) {
            const int f = w + fi * 4;
            const int mblk_l = f & 3, kc_l = f >> 2;
            bfrag fr;
#pragma unroll
            for (int j = 0; j < 8; ++j)
                fr[j] = (short)tile[kc_l * 32 + q * 8 + j][mblk_l * 16 + col];
            const size_t addr = ((size_t)(((b0 >> 4) + mblk_l) * NKC_ + (pd0 >> 5) + kc_l)) * 512 + ln * 8;
            __builtin_nontemporal_store(fr, (bfrag*)(Xb + addr));
        }
    }
}

// ---- GEMM1 + squash. grid (32,5), 1024 thr = 16 waves, 2 n's per block ----
// Natural mapping (mblk = blockIdx.x): each XCD's 20 blocks touch only 4 Xb
// slices + Wc (4.1MB ~ L2) under round-robin dispatch. Do not swizzle (r17).
__global__ __launch_bounds__(1024) void k_sv(const unsigned short* __restrict__ Xb,
                                             const unsigned short* __restrict__ Wc,
                                             unsigned short* __restrict__ Vt,
                                             float* __restrict__ outp,
                                             int final_it) {
    __shared__ float red[16][2][256];   // 32KB: all 16 waves x {n0,n1}
    const int tid = threadIdx.x;
    const int w = tid >> 6, lane = tid & 63, col = lane & 15, q = lane >> 4;
    const int mblk = blockIdx.x;        // 16 b-rows
    const int n0 = blockIdx.y * 2;      // two n per block

    f32x4 accA = (f32x4){0.f, 0.f, 0.f, 0.f};
    f32x4 accB = (f32x4){0.f, 0.f, 0.f, 0.f};
    const int kc0 = w * 18;             // 18 chunks per wave
    const unsigned short* Xp = Xb + ((size_t)(mblk * NKC_ + kc0)) * 512 + lane * 8;
    const unsigned short* W0 = Wc + ((size_t)(n0 * NKC_ + kc0)) * 512 + lane * 8;
    const unsigned short* W1 = W0 + (size_t)NKC_ * 512;
#pragma unroll 3
    for (int i = 0; i < 18; ++i) {
        const bfrag a  = *(const bfrag*)Xp;
        const bfrag b0 = *(const bfrag*)W0;
        const bfrag b1 = *(const bfrag*)W1;
        accA = __builtin_amdgcn_mfma_f32_16x16x32_bf16(a, b0, accA, 0, 0, 0);
        accB = __builtin_amdgcn_mfma_f32_16x16x32_bf16(a, b1, accB, 0, 0, 0);
        Xp += 512; W0 += 512; W1 += 512;
    }
#pragma unroll
    for (int r = 0; r < 4; ++r) {
        red[w][0][r * 64 + q * 16 + col] = accA[r];
        red[w][1][r * 64 + q * 16 + col] = accB[r];
    }
    __syncthreads();
    if (w < 2) {                        // wave 0 -> n0, wave 1 -> n0+1
        const int mt = n0 + w;
#pragma unroll
        for (int r = 0; r < 4; ++r) {
            const int li = r * 64 + q * 16 + col;
            float s = 0.f;
#pragma unroll
            for (int j = 0; j < 16; ++j) s += red[j][w][li];
            float sq = s * s;                      // t = col (16 lanes)
            sq += __shfl_xor(sq, 1);
            sq += __shfl_xor(sq, 2);
            sq += __shfl_xor(sq, 4);
            sq += __shfl_xor(sq, 8);
            const float norm = sqrtf(sq);
            const float scale = sq / (1.0f + sq * (norm + 1e-9f));
            const float vv = s * scale;
            const int b = mblk * 16 + q * 4 + r;
            if (final_it) {
                __builtin_nontemporal_store(vv, outp + (size_t)b * NT_ + mt * 16 + col);
            } else {
                const int b5 = b & 31;             // fragment layout write
                __builtin_nontemporal_store(f2bf(vv),
                    Vt + ((size_t)((mblk >> 1) * N_ + mt)) * 512
                       + ((b5 >> 3) * 16 + col) * 8 + (b5 & 7));
            }
        }
    }
}

// ---- GEMM2 + contraction + softmax + Wc rebuild. grid 192, 768 thr -------
// Three pdblk per block: 192 <= 256 CUs -> SINGLE round (was 288 = 256+32
// two-round tail). Thirds share Vt frags via L1.
__global__ __launch_bounds__(768) void k_ga(const unsigned short* __restrict__ Vt,
                                            const unsigned short* __restrict__ Xga,
                                            const unsigned short* __restrict__ Wb,
                                            const float* __restrict__ W,
                                            float* __restrict__ bbar,
                                            unsigned short* __restrict__ Wc,
                                            int accum) {
    __shared__ float bred[3][3][64][41];   // 126KB; stride 41: conflict-free
    __shared__ float csm[6][N_];
    const int tid = threadIdx.x;
    const int w = tid >> 6, lane = tid & 63, col = lane & 15, q = lane >> 4;
    const int third = w >> 2, wl = w & 3;
    const int pdblk = blockIdx.x * 3 + third;
    const int p = (pdblk * 16 + col) >> 3, d = col & 7;

    f32x4 acc[N_];
#pragma unroll
    for (int mt = 0; mt < N_; ++mt) acc[mt] = (f32x4){0.f, 0.f, 0.f, 0.f};

    const int kb0 = wl * 4;
#pragma unroll
    for (int kc = kb0; kc < kb0 + 4; ++kc) {
        const bfrag bf = *(const bfrag*)(Xga + ((size_t)(pdblk * 16 + kc)) * 512 + lane * 8);
#pragma unroll
        for (int mt = 0; mt < N_; ++mt) {
            const bfrag af = *(const bfrag*)(Vt + ((size_t)(kc * N_ + mt)) * 512 + lane * 8);
            acc[mt] = __builtin_amdgcn_mfma_f32_16x16x32_bf16(af, bf, acc[mt], 0, 0, 0);
        }
    }
    if (wl) {
#pragma unroll
        for (int mt = 0; mt < N_; ++mt)
#pragma unroll
            for (int r = 0; r < 4; ++r)
                bred[third][wl - 1][lane][mt * 4 + r] = acc[mt][r];
    }
    __syncthreads();
    if (wl == 0) {
        unsigned short wv[40];
        const unsigned short* ws2 = Wb + ((size_t)(pdblk * 64 + lane)) * 40;
#pragma unroll
        for (int v = 0; v < 40; ++v) wv[v] = ws2[v];
        float part[N_];
#pragma unroll
        for (int mt = 0; mt < N_; ++mt) {
            float s = 0.f;
#pragma unroll
            for (int r = 0; r < 4; ++r) {
                const float h = acc[mt][r] + bred[third][0][lane][mt * 4 + r]
                              + bred[third][1][lane][mt * 4 + r]
                              + bred[third][2][lane][mt * 4 + r];
                s = fmaf(bf2f(wv[mt * 4 + r]), h, s);
            }
            s += __shfl_xor(s, 1);    // reduce over d
            s += __shfl_xor(s, 2);
            s += __shfl_xor(s, 4);
            s += __shfl_xor(s, 16);   // reduce over t-quarters
            s += __shfl_xor(s, 32);
            part[mt] = s;
        }
        if (q == 0 && d == 0) {       // lanes 0 and 8: this third's 2 p's
            const int pl = col >> 3;
            float bv[N_];
#pragma unroll
            for (int mt = 0; mt < N_; ++mt) {
                bv[mt] = part[mt] * (1.0f / 512.0f);
                if (accum) bv[mt] += bbar[(size_t)p * N_ + mt];
                bbar[(size_t)p * N_ + mt] = bv[mt];
            }
            float m = -1e30f;
#pragma unroll
            for (int mt = 0; mt < N_; ++mt) m = fmaxf(m, bv[mt]);
            float sum = 0.f;
#pragma unroll
            for (int mt = 0; mt < N_; ++mt) { bv[mt] = __expf(bv[mt] - m); sum += bv[mt]; }
            const float inv = 1.f / sum;
#pragma unroll
            for (int mt = 0; mt < N_; ++mt) csm[third * 2 + pl][mt] = bv[mt] * inv;
        }
    }
    __syncthreads();
    const int p0 = blockIdx.x * 6;
#pragma unroll
    for (int task = tid; task < 960; task += 768) {   // Wc rebuild (6 p's)
        const int pl = task / 160, rem = task % 160;
        const int n = rem >> 4, cl = rem & 15;
        const int pp = p0 + pl;
        const float c = csm[pl][n];
        const float* wr = W + ((size_t)pp * NT_ + n * 16 + cl) * 8;
        const size_t addr = ((size_t)(n * NKC_ + (pp >> 2))) * 512 + (pp & 3) * 128 + cl * 8;
        __builtin_nontemporal_store(
            mkfrag(*(const f32x4*)wr, *(const f32x4*)(wr + 4), c),
            (bfrag*)(Wc + addr));
    }
}

extern "C" void kernel_launch(void* const* d_in, const int* in_sizes, int n_in,
                              void* d_out, int out_size, void* d_ws, size_t ws_size,
                              hipStream_t stream) {
    const float* x = (const float*)d_in[0];   // fp32 [B][P*D]
    const float* W = (const float*)d_in[1];   // fp32 [P][NT][D]

    char* wsp = (char*)d_ws;
    float* bbar = (float*)wsp;                                      // 46080 B
    unsigned short* Xb  = (unsigned short*)(wsp + 46080);           // 9.44 MB
    unsigned short* Xga = Xb + (size_t)32 * NKC_ * 512;             // 9.44 MB
    unsigned short* Wc  = Xga + (size_t)576 * 16 * 512;             // 2.95 MB
    unsigned short* Wb  = Wc + (size_t)N_ * NKC_ * 512;             // 2.95 MB
    unsigned short* Vt  = Wb + (size_t)576 * 64 * 40;               // 160 KB
    float* outp = (float*)d_out;

    k_prep<<<dim3(1440), dim3(256), 0, stream>>>(x, W, Xb, Xga, Wc, Wb);
    k_sv<<<dim3(32, 5), dim3(1024), 0, stream>>>(Xb, Wc, Vt, outp, 0);
    k_ga<<<dim3(192), dim3(768), 0, stream>>>(Vt, Xga, Wb, W, bbar, Wc, 0);
    k_sv<<<dim3(32, 5), dim3(1024), 0, stream>>>(Xb, Wc, Vt, outp, 0);
    k_ga<<<dim3(192), dim3(768), 0, stream>>>(Vt, Xga, Wb, W, bbar, Wc, 1);
    k_sv<<<dim3(32, 5), dim3(1024), 0, stream>>>(Xb, Wc, Vt, outp, 1);
}

// Round 7
// 136.321 us; speedup vs baseline: 1.1179x; 1.1179x over previous
//
#include <hip/hip_runtime.h>
#include <hip/hip_bf16.h>

// CapsuleLayer routing, bf16 MFMA, 6 dispatches.
// B=512,P=1152,N=10,T=16,D=8, 3 iters. Verified 16x16x32 bf16 layouts:
//   A: m=lane&15, k=q*8+j   B: n=lane&15, k=q*8+j   D: col=lane&15, row=q*4+r
// r20: ELIMINATE the per-iteration Wc rebuild cycle via A-side scaling.
//   mfma(x, bf16(c*W)) == mfma(bf16(c*x), bf16(W)) since all 8 elems of a
//   lane's A-frag share p = kc*4+q -> c is a per-lane SCALAR.
//   - prep writes Wst = bf16(W) frags (static) + Wc0 = bf16(0.1W) (static).
//   - ga writes only csm[p][n] (46KB) -- no Wc rebuild, no W reads.
//   - sv iter0 = old path (Wc0, bit-identical); iters 1/2 read Wst + csm and
//     scale the x-frag. Cross-dispatch rewritten bytes drop ~6MB -> ~0.25MB.
// History: r15 traffic cut -18.6us => cross-dispatch bytes cost ~2.5TB/s;
// r19 nontemporal REGRESSED +19us (nt evicts past L3; keep stores cached);
// r16 grid-halving REGRESSED (coverage); r17 XCD swizzle regressed (natural
// mblk%8 mapping already L2-optimal); r14 TLP/LDS-pad neutral; r11 grid-sync 4x.

typedef __attribute__((ext_vector_type(8))) short bfrag;   // 8 bf16
typedef __attribute__((ext_vector_type(4))) float f32x4;

constexpr int B_ = 512, P_ = 1152, N_ = 10, NT_ = 160;
constexpr int K1_ = 9216, NKC_ = 288;

__device__ __forceinline__ unsigned short f2bf(float f) {
    unsigned u = __float_as_uint(f);
    return (unsigned short)((u + 0x7fffu + ((u >> 16) & 1u)) >> 16);  // RNE
}
__device__ __forceinline__ float bf2f(unsigned short s) {
    return __uint_as_float((unsigned)s << 16);
}

// Xb:  [mblk 32][kc 288][lane 64][8]  elem = x[mblk*16+col][kc*32+q*8+j]
// Xga: [pdblk 576][kc 16][lane 64][8] elem = x[kc*32+q*8+j][pdblk*16+col]
// Wc0: [n 10][kc 288][lane 64][8]     elem = 0.1*W[p][n*16+col][j], p=kc*4+q
// Wst: [n 10][kc 288][lane 64][8]     elem =     W[p][n*16+col][j]  (static)
// Wb:  [pdblk 576][lane 64][40]       elem(mt*4+r) = W[p][mt*16+q*4+r][d]
// Vt:  [kc 16][mt 10][lane 64][8]     elem = v[kc*32+q*8+j][mt*16+col]  (bf16)
// csm: [p 1152][n 10] fp32 softmax coefficients (ga -> sv)
__global__ __launch_bounds__(256) void k_prep(const float* __restrict__ x,
                                              const float* __restrict__ W,
                                              unsigned short* __restrict__ Xb,
                                              unsigned short* __restrict__ Xga,
                                              unsigned short* __restrict__ Wc0,
                                              unsigned short* __restrict__ Wst,
                                              unsigned short* __restrict__ Wb) {
    __shared__ float smem[5760];   // 23 KB: fused-W stage OR x-transpose tile
    const int bid = blockIdx.x, tid = threadIdx.x;
    const int w = tid >> 6, ln = tid & 63, col = ln & 15, q = ln >> 4;
    if (bid < 288) {           // fused W branch: 4 p's per block, W read once
        const int pb = bid;            // == kc for Wc0/Wst
        const int p0 = pb * 4;
        // stage W[p0..p0+3] (5120 floats) coalesced -> LDS stride-9 pad
#pragma unroll
        for (int k = 0; k < 20; ++k) {
            const int e = k * 256 + tid;          // [0,5120)
            const int pl = e / 1280, rem = e % 1280;
            const int row = rem >> 3, d = rem & 7;
            smem[pl * 1440 + row * 9 + d] = W[(size_t)p0 * 1280 + e];
        }
        __syncthreads();
        // Wc0 = bf16(0.1*W), Wst = bf16(W): 10 (n) tasks over 4 waves; p=p0+q
        for (int n = w; n < N_; n += 4) {
            const float* src = smem + q * 1440 + (n * 16 + col) * 9;
            bfrag f0, f1;
#pragma unroll
            for (int j = 0; j < 8; ++j) {
                const float v = src[j];
                f0[j] = (short)f2bf(v * 0.1f);
                f1[j] = (short)f2bf(v);
            }
            const size_t addr = ((size_t)(n * NKC_ + pb)) * 512 + ln * 8;
            *(bfrag*)(Wc0 + addr) = f0;
            *(bfrag*)(Wst + addr) = f1;
        }
        // Wb: this block covers pdblk 2*pb + {0,1}; threads 0..127 emit
        if (tid < 128) {
            const int pdblk_l = tid >> 6;          // 0..1
            const int lane = tid & 63, c2 = lane & 15, q2 = lane >> 4;
            const int p_l = (pdblk_l * 16 + c2) >> 3, d = c2 & 7;
            const float* src = smem + p_l * 1440 + d;
            unsigned short* dst = Wb + ((size_t)((2 * pb + pdblk_l) * 64 + lane)) * 40;
#pragma unroll
            for (int mt = 0; mt < N_; ++mt)
#pragma unroll
                for (int r = 0; r < 4; ++r)
                    dst[mt * 4 + r] = f2bf(src[(mt * 16 + q2 * 4 + r) * 9]);
        }
    } else {                   // x transpose tile -> Xga AND Xb fragments
        unsigned short (*tile)[72] = (unsigned short (*)[72])smem;  // 64x72
        const int tb = bid - 288;
        const int pd0 = (tb >> 3) * 64, b0 = (tb & 7) * 64;
        const int c0 = tid & 63, r0 = tid >> 6;
#pragma unroll
        for (int i = 0; i < 16; ++i) {
            const int br = i * 4 + r0;   // coalesced: 64 lanes x 4B contiguous
            tile[c0][br] = f2bf(x[(size_t)(b0 + br) * K1_ + pd0 + c0]);
        }
        __syncthreads();
        // Xga: 8 frags (pdblk_l 0..3, kc_l 0..1); wave w does f=w, f=w+4
#pragma unroll
        for (int fi = 0; fi < 2; ++fi) {
            const int f = w + fi * 4;
            const int pdblk_l = f & 3, kc_l = f >> 2;
            bfrag fr;
#pragma unroll
            for (int j = 0; j < 8; ++j)
                fr[j] = (short)tile[pdblk_l * 16 + col][kc_l * 32 + q * 8 + j];
            const size_t addr = ((size_t)(((pd0 >> 4) + pdblk_l) * 16 + (b0 >> 5) + kc_l)) * 512 + ln * 8;
            *(bfrag*)(Xga + addr) = fr;   // 1KB/wave contiguous
        }
        // Xb: 8 frags (mblk_l 0..3, kc_l 0..1); wave w does f=w, f=w+4
#pragma unroll
        for (int fi = 0; fi < 2; ++fi) {
            const int f = w + fi * 4;
            const int mblk_l = f & 3, kc_l = f >> 2;
            bfrag fr;
#pragma unroll
            for (int j = 0; j < 8; ++j)
                fr[j] = (short)tile[kc_l * 32 + q * 8 + j][mblk_l * 16 + col];
            const size_t addr = ((size_t)(((b0 >> 4) + mblk_l) * NKC_ + (pd0 >> 5) + kc_l)) * 512 + ln * 8;
            *(bfrag*)(Xb + addr) = fr;    // 1KB/wave contiguous
        }
    }
}

// ---- GEMM1 + squash. grid (32,5), 1024 thr = 16 waves, 2 n's per block ----
// mode 0: W-frags are pre-scaled Wc0 (bit-identical iter0 path).
// mode 1/2: W-frags are static Wst; scale x-frag by c = csm[kc*4+q][n]
// (all 8 A-elems of a lane share p -> per-lane scalar). mode 2 -> outp.
__global__ __launch_bounds__(1024) void k_sv(const unsigned short* __restrict__ Xb,
                                             const unsigned short* __restrict__ Wf,
                                             const float* __restrict__ csm,
                                             unsigned short* __restrict__ Vt,
                                             float* __restrict__ outp,
                                             int mode) {
    __shared__ float red[16][2][256];   // 32KB: all 16 waves x {n0,n1}
    const int tid = threadIdx.x;
    const int w = tid >> 6, lane = tid & 63, col = lane & 15, q = lane >> 4;
    const int mblk = blockIdx.x;        // 16 b-rows
    const int n0 = blockIdx.y * 2;      // two n per block

    f32x4 accA = (f32x4){0.f, 0.f, 0.f, 0.f};
    f32x4 accB = (f32x4){0.f, 0.f, 0.f, 0.f};
    const int kc0 = w * 18;             // 18 chunks per wave
    const unsigned short* Xp = Xb + ((size_t)(mblk * NKC_ + kc0)) * 512 + lane * 8;
    const unsigned short* W0 = Wf + ((size_t)(n0 * NKC_ + kc0)) * 512 + lane * 8;
    const unsigned short* W1 = W0 + (size_t)NKC_ * 512;
    if (mode == 0) {
#pragma unroll 3
        for (int i = 0; i < 18; ++i) {
            const bfrag a  = *(const bfrag*)Xp;
            const bfrag b0 = *(const bfrag*)W0;
            const bfrag b1 = *(const bfrag*)W1;
            accA = __builtin_amdgcn_mfma_f32_16x16x32_bf16(a, b0, accA, 0, 0, 0);
            accB = __builtin_amdgcn_mfma_f32_16x16x32_bf16(a, b1, accB, 0, 0, 0);
            Xp += 512; W0 += 512; W1 += 512;
        }
    } else {
        // c pointer: p = kc*4 + q, addr = (p*10 + n0)*4B; n0 even -> 8B aligned
        const float* cp = csm + ((size_t)(kc0 * 4 + q)) * N_ + n0;
#pragma unroll 3
        for (int i = 0; i < 18; ++i) {
            const bfrag a  = *(const bfrag*)Xp;
            const bfrag b0 = *(const bfrag*)W0;
            const bfrag b1 = *(const bfrag*)W1;
            const float2 cc = *(const float2*)cp;   // c[n0], c[n0+1] broadcast
            bfrag a0, a1;
#pragma unroll
            for (int j = 0; j < 8; ++j) {
                const float xf = bf2f((unsigned short)a[j]);
                a0[j] = (short)f2bf(xf * cc.x);
                a1[j] = (short)f2bf(xf * cc.y);
            }
            accA = __builtin_amdgcn_mfma_f32_16x16x32_bf16(a0, b0, accA, 0, 0, 0);
            accB = __builtin_amdgcn_mfma_f32_16x16x32_bf16(a1, b1, accB, 0, 0, 0);
            Xp += 512; W0 += 512; W1 += 512; cp += 40;   // next kc: p += 4
        }
    }
#pragma unroll
    for (int r = 0; r < 4; ++r) {
        red[w][0][r * 64 + q * 16 + col] = accA[r];
        red[w][1][r * 64 + q * 16 + col] = accB[r];
    }
    __syncthreads();
    if (w < 2) {                        // wave 0 -> n0, wave 1 -> n0+1
        const int mt = n0 + w;
#pragma unroll
        for (int r = 0; r < 4; ++r) {
            const int li = r * 64 + q * 16 + col;
            float s = 0.f;
#pragma unroll
            for (int j = 0; j < 16; ++j) s += red[j][w][li];
            float sq = s * s;                      // t = col (16 lanes)
            sq += __shfl_xor(sq, 1);
            sq += __shfl_xor(sq, 2);
            sq += __shfl_xor(sq, 4);
            sq += __shfl_xor(sq, 8);
            const float norm = sqrtf(sq);
            const float scale = sq / (1.0f + sq * (norm + 1e-9f));
            const float vv = s * scale;
            const int b = mblk * 16 + q * 4 + r;
            if (mode == 2) {
                outp[(size_t)b * NT_ + mt * 16 + col] = vv;
            } else {
                const int b5 = b & 31;             // fragment layout write
                Vt[((size_t)((mblk >> 1) * N_ + mt)) * 512
                   + ((b5 >> 3) * 16 + col) * 8 + (b5 & 7)] = f2bf(vv);
            }
        }
    }
}

// ---- GEMM2 + contraction + softmax. grid 192, 768 thr --------------------
// Three pdblk per block (single round). Output is just csm (46KB) + bbar --
// the Wc rebuild is GONE (sv scales its A-fragments by csm instead).
__global__ __launch_bounds__(768) void k_ga(const unsigned short* __restrict__ Vt,
                                            const unsigned short* __restrict__ Xga,
                                            const unsigned short* __restrict__ Wb,
                                            float* __restrict__ bbar,
                                            float* __restrict__ csm_g,
                                            int accum) {
    __shared__ float bred[3][3][64][41];   // 126KB; stride 41: conflict-free
    const int tid = threadIdx.x;
    const int w = tid >> 6, lane = tid & 63, col = lane & 15, q = lane >> 4;
    const int third = w >> 2, wl = w & 3;
    const int pdblk = blockIdx.x * 3 + third;
    const int p = (pdblk * 16 + col) >> 3, d = col & 7;

    f32x4 acc[N_];
#pragma unroll
    for (int mt = 0; mt < N_; ++mt) acc[mt] = (f32x4){0.f, 0.f, 0.f, 0.f};

    const int kb0 = wl * 4;
#pragma unroll
    for (int kc = kb0; kc < kb0 + 4; ++kc) {
        const bfrag bf = *(const bfrag*)(Xga + ((size_t)(pdblk * 16 + kc)) * 512 + lane * 8);
#pragma unroll
        for (int mt = 0; mt < N_; ++mt) {
            const bfrag af = *(const bfrag*)(Vt + ((size_t)(kc * N_ + mt)) * 512 + lane * 8);
            acc[mt] = __builtin_amdgcn_mfma_f32_16x16x32_bf16(af, bf, acc[mt], 0, 0, 0);
        }
    }
    if (wl) {
#pragma unroll
        for (int mt = 0; mt < N_; ++mt)
#pragma unroll
            for (int r = 0; r < 4; ++r)
                bred[third][wl - 1][lane][mt * 4 + r] = acc[mt][r];
    }
    __syncthreads();
    if (wl == 0) {
        unsigned short wv[40];
        const unsigned short* ws2 = Wb + ((size_t)(pdblk * 64 + lane)) * 40;
#pragma unroll
        for (int v = 0; v < 40; ++v) wv[v] = ws2[v];
        float part[N_];
#pragma unroll
        for (int mt = 0; mt < N_; ++mt) {
            float s = 0.f;
#pragma unroll
            for (int r = 0; r < 4; ++r) {
                const float h = acc[mt][r] + bred[third][0][lane][mt * 4 + r]
                              + bred[third][1][lane][mt * 4 + r]
                              + bred[third][2][lane][mt * 4 + r];
                s = fmaf(bf2f(wv[mt * 4 + r]), h, s);
            }
            s += __shfl_xor(s, 1);    // reduce over d
            s += __shfl_xor(s, 2);
            s += __shfl_xor(s, 4);
            s += __shfl_xor(s, 16);   // reduce over t-quarters
            s += __shfl_xor(s, 32);
            part[mt] = s;
        }
        if (q == 0 && d == 0) {       // lanes 0 and 8: this third's 2 p's
            float bv[N_];
#pragma unroll
            for (int mt = 0; mt < N_; ++mt) {
                bv[mt] = part[mt] * (1.0f / 512.0f);
                if (accum) bv[mt] += bbar[(size_t)p * N_ + mt];
                bbar[(size_t)p * N_ + mt] = bv[mt];
            }
            float m = -1e30f;
#pragma unroll
            for (int mt = 0; mt < N_; ++mt) m = fmaxf(m, bv[mt]);
            float sum = 0.f;
#pragma unroll
            for (int mt = 0; mt < N_; ++mt) { bv[mt] = __expf(bv[mt] - m); sum += bv[mt]; }
            const float inv = 1.f / sum;
#pragma unroll
            for (int mt = 0; mt < N_; ++mt)
                csm_g[(size_t)p * N_ + mt] = bv[mt] * inv;
        }
    }
}

extern "C" void kernel_launch(void* const* d_in, const int* in_sizes, int n_in,
                              void* d_out, int out_size, void* d_ws, size_t ws_size,
                              hipStream_t stream) {
    const float* x = (const float*)d_in[0];   // fp32 [B][P*D]
    const float* W = (const float*)d_in[1];   // fp32 [P][NT][D]

    char* wsp = (char*)d_ws;
    float* bbar = (float*)wsp;                                      // 46080 B
    float* csm  = (float*)(wsp + 46080);                            // 46080 B
    unsigned short* Xb  = (unsigned short*)(wsp + 92160);           // 9.44 MB
    unsigned short* Xga = Xb + (size_t)32 * NKC_ * 512;             // 9.44 MB
    unsigned short* Wc0 = Xga + (size_t)576 * 16 * 512;             // 2.95 MB
    unsigned short* Wst = Wc0 + (size_t)N_ * NKC_ * 512;            // 2.95 MB
    unsigned short* Wb  = Wst + (size_t)N_ * NKC_ * 512;            // 2.95 MB
    unsigned short* Vt  = Wb + (size_t)576 * 64 * 40;               // 160 KB
    float* outp = (float*)d_out;

    k_prep<<<dim3(1440), dim3(256), 0, stream>>>(x, W, Xb, Xga, Wc0, Wst, Wb);
    k_sv<<<dim3(32, 5), dim3(1024), 0, stream>>>(Xb, Wc0, csm, Vt, outp, 0);
    k_ga<<<dim3(192), dim3(768), 0, stream>>>(Vt, Xga, Wb, bbar, csm, 0);
    k_sv<<<dim3(32, 5), dim3(1024), 0, stream>>>(Xb, Wst, csm, Vt, outp, 1);
    k_ga<<<dim3(192), dim3(768), 0, stream>>>(Vt, Xga, Wb, bbar, csm, 1);
    k_sv<<<dim3(32, 5), dim3(1024), 0, stream>>>(Xb, Wst, csm, Vt, outp, 2);
}

// Round 8
// 134.210 us; speedup vs baseline: 1.1355x; 1.0157x over previous
//
#include <hip/hip_runtime.h>
#include <hip/hip_bf16.h>

// CapsuleLayer routing, bf16 MFMA, 6 dispatches.
// B=512,P=1152,N=10,T=16,D=8, 3 iters. Verified 16x16x32 bf16 layouts:
//   A: m=lane&15, k=q*8+j   B: n=lane&15, k=q*8+j   D: col=lane&15, row=q*4+r
// r21 = r18 base (133.4us best; r20's A-side scaling reverted, +2.9us) with
// k_ga rebuilt around LDS staging:
//   - 288 blocks x 640 thr = 10 waves (2 pdblk x 5 mt-groups). Each wave owns
//     2 mt over FULL K (16 kc) -> bred eliminated (126KB LDS freed).
//   - Vt+Xga staged per-kc to LDS (24KB double-buffer): the 3x-replicated
//     global Vt stream (480KB L1-side per block for 160KB distinct) becomes
//     one global read + LDS-pipe reads. Wb repacked [pdblk][mtg][lane][8] so
//     a wave loads exactly its 16B/lane (was 8 of 40 per 80B row).
//   - ga L1-side ~104 -> ~68 MB/dispatch; 25KB-LDS blocks are 3-resident
//     (192x126KB was 1-resident, 64 CUs idle).
// k_sv unchanged (PROVEN at its tiling optimum: minimize (m+n) s.t. mn=512
// per block at >=160-block coverage -> 16x32 tile). k_prep: only Wb2 reorder.
// History: r15 traffic cut -18.6us => ~12.5TB/s marginal vector-mem pipe;
// r16 grid-halving REGRESSED (coverage); r17 XCD swizzle regressed (natural
// mblk%8 mapping already L2-optimal); r19 nontemporal REGRESSED +19us (nt
// evicts past L3); r20 Wc-cycle elimination REGRESSED +2.9us (cycle was
// cheap); r14 TLP/LDS-pad neutral; r11 grid-sync 4x.

typedef __attribute__((ext_vector_type(8))) short bfrag;   // 8 bf16
typedef __attribute__((ext_vector_type(4))) float f32x4;

constexpr int B_ = 512, P_ = 1152, N_ = 10, NT_ = 160;
constexpr int K1_ = 9216, NKC_ = 288;

__device__ __forceinline__ unsigned short f2bf(float f) {
    unsigned u = __float_as_uint(f);
    return (unsigned short)((u + 0x7fffu + ((u >> 16) & 1u)) >> 16);  // RNE
}
__device__ __forceinline__ float bf2f(unsigned short s) {
    return __uint_as_float((unsigned)s << 16);
}
__device__ __forceinline__ bfrag mkfrag(f32x4 a, f32x4 b, float c) {
    bfrag f;
    f[0] = (short)f2bf(a.x * c); f[1] = (short)f2bf(a.y * c);
    f[2] = (short)f2bf(a.z * c); f[3] = (short)f2bf(a.w * c);
    f[4] = (short)f2bf(b.x * c); f[5] = (short)f2bf(b.y * c);
    f[6] = (short)f2bf(b.z * c); f[7] = (short)f2bf(b.w * c);
    return f;
}

// Xb:  [mblk 32][kc 288][lane 64][8]  elem = x[mblk*16+col][kc*32+q*8+j]
// Xga: [pdblk 576][kc 16][lane 64][8] elem = x[kc*32+q*8+j][pdblk*16+col]
// Wc:  [n 10][kc 288][lane 64][8]     elem = c[p,n]*W[p][n*16+col][j], p=kc*4+q
// Wb2: [pdblk 576][mtg 5][lane 64][8] elem(ml*4+r) = W[p][(mtg*2+ml)*16+q*4+r][d]
// Vt:  [kc 16][mt 10][lane 64][8]     elem = v[kc*32+q*8+j][mt*16+col]  (bf16)
__global__ __launch_bounds__(256) void k_prep(const float* __restrict__ x,
                                              const float* __restrict__ W,
                                              unsigned short* __restrict__ Xb,
                                              unsigned short* __restrict__ Xga,
                                              unsigned short* __restrict__ Wc,
                                              unsigned short* __restrict__ Wb2) {
    __shared__ float smem[5760];   // 23 KB: fused-W stage OR x-transpose tile
    const int bid = blockIdx.x, tid = threadIdx.x;
    const int w = tid >> 6, ln = tid & 63, col = ln & 15, q = ln >> 4;
    if (bid < 288) {           // fused W branch: 4 p's per block, W read once
        const int pb = bid;            // == kc for Wc0
        const int p0 = pb * 4;
        // stage W[p0..p0+3] (5120 floats) coalesced -> LDS stride-9 pad
#pragma unroll
        for (int k = 0; k < 20; ++k) {
            const int e = k * 256 + tid;          // [0,5120)
            const int pl = e / 1280, rem = e % 1280;
            const int row = rem >> 3, d = rem & 7;
            smem[pl * 1440 + row * 9 + d] = W[(size_t)p0 * 1280 + e];
        }
        __syncthreads();
        // Wc0 = bf16(0.1*W): 10 (n) tasks over 4 waves; p = p0 + q
        for (int n = w; n < N_; n += 4) {
            const float* src = smem + q * 1440 + (n * 16 + col) * 9;
            bfrag f;
#pragma unroll
            for (int j = 0; j < 8; ++j) f[j] = (short)f2bf(src[j] * 0.1f);
            *(bfrag*)(Wc + ((size_t)(n * NKC_ + pb)) * 512 + ln * 8) = f;
        }
        // Wb2: this block covers pdblk 2*pb + {0,1}; threads 0..127 emit
        if (tid < 128) {
            const int pdblk_l = tid >> 6;          // 0..1
            const int lane = tid & 63, c2 = lane & 15, q2 = lane >> 4;
            const int p_l = (pdblk_l * 16 + c2) >> 3, d = c2 & 7;
            const float* src = smem + p_l * 1440 + d;
#pragma unroll
            for (int mtg = 0; mtg < 5; ++mtg) {
                bfrag f;
#pragma unroll
                for (int ml = 0; ml < 2; ++ml)
#pragma unroll
                    for (int r = 0; r < 4; ++r)
                        f[ml * 4 + r] = (short)f2bf(src[((mtg * 2 + ml) * 16 + q2 * 4 + r) * 9]);
                *(bfrag*)(Wb2 + ((size_t)((2 * pb + pdblk_l) * 5 + mtg) * 64 + lane) * 8) = f;
            }
        }
    } else {                   // x transpose tile -> Xga AND Xb fragments
        unsigned short (*tile)[72] = (unsigned short (*)[72])smem;  // 64x72
        const int tb = bid - 288;
        const int pd0 = (tb >> 3) * 64, b0 = (tb & 7) * 64;
        const int c0 = tid & 63, r0 = tid >> 6;
#pragma unroll
        for (int i = 0; i < 16; ++i) {
            const int br = i * 4 + r0;   // coalesced: 64 lanes x 4B contiguous
            tile[c0][br] = f2bf(x[(size_t)(b0 + br) * K1_ + pd0 + c0]);
        }
        __syncthreads();
        // Xga: 8 frags (pdblk_l 0..3, kc_l 0..1); wave w does f=w, f=w+4
#pragma unroll
        for (int fi = 0; fi < 2; ++fi) {
            const int f = w + fi * 4;
            const int pdblk_l = f & 3, kc_l = f >> 2;
            bfrag fr;
#pragma unroll
            for (int j = 0; j < 8; ++j)
                fr[j] = (short)tile[pdblk_l * 16 + col][kc_l * 32 + q * 8 + j];
            const size_t addr = ((size_t)(((pd0 >> 4) + pdblk_l) * 16 + (b0 >> 5) + kc_l)) * 512 + ln * 8;
            *(bfrag*)(Xga + addr) = fr;   // 1KB/wave contiguous
        }
        // Xb: 8 frags (mblk_l 0..3, kc_l 0..1); wave w does f=w, f=w+4
#pragma unroll
        for (int fi = 0; fi < 2; ++fi) {
            const int f = w + fi * 4;
            const int mblk_l = f & 3, kc_l = f >> 2;
            bfrag fr;
#pragma unroll
            for (int j = 0; j < 8; ++j)
                fr[j] = (short)tile[kc_l * 32 + q * 8 + j][mblk_l * 16 + col];
            const size_t addr = ((size_t)(((b0 >> 4) + mblk_l) * NKC_ + (pd0 >> 5) + kc_l)) * 512 + ln * 8;
            *(bfrag*)(Xb + addr) = fr;    // 1KB/wave contiguous
        }
    }
}

// ---- GEMM1 + squash. grid (32,5), 1024 thr = 16 waves, 2 n's per block ----
// Natural mapping (mblk = blockIdx.x): each XCD's 20 blocks touch only 4 Xb
// slices + Wc (4.1MB ~ L2) under round-robin dispatch. Do not swizzle (r17).
__global__ __launch_bounds__(1024) void k_sv(const unsigned short* __restrict__ Xb,
                                             const unsigned short* __restrict__ Wc,
                                             unsigned short* __restrict__ Vt,
                                             float* __restrict__ outp,
                                             int final_it) {
    __shared__ float red[16][2][256];   // 32KB: all 16 waves x {n0,n1}
    const int tid = threadIdx.x;
    const int w = tid >> 6, lane = tid & 63, col = lane & 15, q = lane >> 4;
    const int mblk = blockIdx.x;        // 16 b-rows
    const int n0 = blockIdx.y * 2;      // two n per block

    f32x4 accA = (f32x4){0.f, 0.f, 0.f, 0.f};
    f32x4 accB = (f32x4){0.f, 0.f, 0.f, 0.f};
    const int kc0 = w * 18;             // 18 chunks per wave
    const unsigned short* Xp = Xb + ((size_t)(mblk * NKC_ + kc0)) * 512 + lane * 8;
    const unsigned short* W0 = Wc + ((size_t)(n0 * NKC_ + kc0)) * 512 + lane * 8;
    const unsigned short* W1 = W0 + (size_t)NKC_ * 512;
#pragma unroll 3
    for (int i = 0; i < 18; ++i) {
        const bfrag a  = *(const bfrag*)Xp;
        const bfrag b0 = *(const bfrag*)W0;
        const bfrag b1 = *(const bfrag*)W1;
        accA = __builtin_amdgcn_mfma_f32_16x16x32_bf16(a, b0, accA, 0, 0, 0);
        accB = __builtin_amdgcn_mfma_f32_16x16x32_bf16(a, b1, accB, 0, 0, 0);
        Xp += 512; W0 += 512; W1 += 512;
    }
#pragma unroll
    for (int r = 0; r < 4; ++r) {
        red[w][0][r * 64 + q * 16 + col] = accA[r];
        red[w][1][r * 64 + q * 16 + col] = accB[r];
    }
    __syncthreads();
    if (w < 2) {                        // wave 0 -> n0, wave 1 -> n0+1
        const int mt = n0 + w;
#pragma unroll
        for (int r = 0; r < 4; ++r) {
            const int li = r * 64 + q * 16 + col;
            float s = 0.f;
#pragma unroll
            for (int j = 0; j < 16; ++j) s += red[j][w][li];
            float sq = s * s;                      // t = col (16 lanes)
            sq += __shfl_xor(sq, 1);
            sq += __shfl_xor(sq, 2);
            sq += __shfl_xor(sq, 4);
            sq += __shfl_xor(sq, 8);
            const float norm = sqrtf(sq);
            const float scale = sq / (1.0f + sq * (norm + 1e-9f));
            const float vv = s * scale;
            const int b = mblk * 16 + q * 4 + r;
            if (final_it) {
                outp[(size_t)b * NT_ + mt * 16 + col] = vv;
            } else {
                const int b5 = b & 31;             // fragment layout write
                Vt[((size_t)((mblk >> 1) * N_ + mt)) * 512
                   + ((b5 >> 3) * 16 + col) * 8 + (b5 & 7)] = f2bf(vv);
            }
        }
    }
}

// ---- GEMM2 + contraction + softmax + Wc rebuild. grid 288, 640 thr -------
// 10 waves = (pdh 2) x (mtg 5); each wave: 2 mt over full K=16 kc (no bred).
// Per-kc Vt(10KB)+Xga(2KB) chunks double-buffered in LDS; all waves ds_read.
__global__ __launch_bounds__(640) void k_ga(const unsigned short* __restrict__ Vt,
                                            const unsigned short* __restrict__ Xga,
                                            const unsigned short* __restrict__ Wb2,
                                            const float* __restrict__ W,
                                            float* __restrict__ bbar,
                                            unsigned short* __restrict__ Wc,
                                            int accum) {
    __shared__ unsigned short stage[2][6144];   // [buf][vt 0..5120 | xga 5120..6144]
    __shared__ float csm_part[2][2][N_];
    __shared__ float csm_l[4][N_];
    const int tid = threadIdx.x;
    const int w = tid >> 6, ln = tid & 63, col = ln & 15, q = ln >> 4;
    const int pdh = w / 5, mtg = w % 5;
    const int bx = blockIdx.x;
    const int pdblk = bx * 2 + pdh;
    const int mt0 = mtg * 2;

    // chunk frag f in [0,768): f<640 -> Vt frag (mt=f>>6, lane=f&63);
    // f>=640 -> Xga frag (pdl=(f-640)>>6, lane). Thread t: f=t and f=t+640.
    const unsigned short* vsrc0 = Vt + (size_t)(tid >> 6) * 512 + (tid & 63) * 8;
    const unsigned short* xsrc0 = (tid < 128)
        ? Xga + ((size_t)((bx * 2 + (tid >> 6)) * 16)) * 512 + (tid & 63) * 8
        : nullptr;

    // prologue: stage chunk 0
    bfrag pa = *(const bfrag*)vsrc0;
    bfrag pb;
    if (tid < 128) pb = *(const bfrag*)xsrc0;
    *(bfrag*)(&stage[0][tid * 8]) = pa;
    if (tid < 128) *(bfrag*)(&stage[0][(640 + tid) * 8]) = pb;
    __syncthreads();

    f32x4 acc0 = (f32x4){0.f, 0.f, 0.f, 0.f};
    f32x4 acc1 = (f32x4){0.f, 0.f, 0.f, 0.f};
    for (int kc = 0; kc < 16; ++kc) {
        if (kc < 15) {   // prefetch next chunk into regs (Vt row += 10*512)
            pa = *(const bfrag*)(vsrc0 + (size_t)(kc + 1) * N_ * 512);
            if (tid < 128) pb = *(const bfrag*)(xsrc0 + (size_t)(kc + 1) * 512);
        }
        const unsigned short* sb = stage[kc & 1];
        const bfrag bf  = *(const bfrag*)(sb + (640 + pdh * 64 + ln) * 8);
        const bfrag af0 = *(const bfrag*)(sb + (mt0 * 64 + ln) * 8);
        const bfrag af1 = *(const bfrag*)(sb + ((mt0 + 1) * 64 + ln) * 8);
        acc0 = __builtin_amdgcn_mfma_f32_16x16x32_bf16(af0, bf, acc0, 0, 0, 0);
        acc1 = __builtin_amdgcn_mfma_f32_16x16x32_bf16(af1, bf, acc1, 0, 0, 0);
        if (kc < 15) {
            __syncthreads();                     // everyone done reading sb
            unsigned short* db = stage[(kc + 1) & 1];
            *(bfrag*)(&db[tid * 8]) = pa;
            if (tid < 128) *(bfrag*)(&db[(640 + tid) * 8]) = pb;
            __syncthreads();                     // chunk kc+1 visible
        }
    }

    // contraction s = sum_r wb*acc_ml[r]; reduce d (xor1,2,4), t-qtrs (16,32)
    const bfrag wv = *(const bfrag*)(Wb2 + ((size_t)(pdblk * 5 + mtg) * 64 + ln) * 8);
    float part[2];
#pragma unroll
    for (int ml = 0; ml < 2; ++ml) {
        const f32x4 a = ml ? acc1 : acc0;
        float s = 0.f;
#pragma unroll
        for (int r = 0; r < 4; ++r)
            s = fmaf(bf2f((unsigned short)wv[ml * 4 + r]), a[r], s);
        s += __shfl_xor(s, 1);
        s += __shfl_xor(s, 2);
        s += __shfl_xor(s, 4);
        s += __shfl_xor(s, 16);
        s += __shfl_xor(s, 32);
        part[ml] = s;
    }
    if (q == 0 && (col & 7) == 0) {   // lanes 0 and 8: the 2 p's of this pdblk
        const int pl = col >> 3;
        csm_part[pdh][pl][mt0] = part[0];
        csm_part[pdh][pl][mt0 + 1] = part[1];
    }
    __syncthreads();
    if (tid < 4) {                    // softmax for the block's 4 p's
        const int ph = tid >> 1, pl = tid & 1;
        const int p = bx * 4 + ph * 2 + pl;
        float bv[N_];
#pragma unroll
        for (int mt = 0; mt < N_; ++mt) {
            bv[mt] = csm_part[ph][pl][mt] * (1.0f / 512.0f);
            if (accum) bv[mt] += bbar[(size_t)p * N_ + mt];
            bbar[(size_t)p * N_ + mt] = bv[mt];
        }
        float m = -1e30f;
#pragma unroll
        for (int mt = 0; mt < N_; ++mt) m = fmaxf(m, bv[mt]);
        float sum = 0.f;
#pragma unroll
        for (int mt = 0; mt < N_; ++mt) { bv[mt] = __expf(bv[mt] - m); sum += bv[mt]; }
        const float inv = 1.f / sum;
#pragma unroll
        for (int mt = 0; mt < N_; ++mt) csm_l[tid][mt] = bv[mt] * inv;
    }
    __syncthreads();
    // Wc rebuild: 640 tasks = 4 p's x 160 (n,cl); kc = p>>2 == bx here
    {
        const int pl4 = tid / 160, rem = tid % 160;
        const int n = rem >> 4, cl = rem & 15;
        const int pp = bx * 4 + pl4;
        const float c = csm_l[pl4][n];
        const float* wr = W + ((size_t)pp * NT_ + n * 16 + cl) * 8;
        const size_t addr = ((size_t)(n * NKC_ + (pp >> 2))) * 512 + (pp & 3) * 128 + cl * 8;
        *(bfrag*)(Wc + addr) = mkfrag(*(const f32x4*)wr, *(const f32x4*)(wr + 4), c);
    }
}

extern "C" void kernel_launch(void* const* d_in, const int* in_sizes, int n_in,
                              void* d_out, int out_size, void* d_ws, size_t ws_size,
                              hipStream_t stream) {
    const float* x = (const float*)d_in[0];   // fp32 [B][P*D]
    const float* W = (const float*)d_in[1];   // fp32 [P][NT][D]

    char* wsp = (char*)d_ws;
    float* bbar = (float*)wsp;                                      // 46080 B
    unsigned short* Xb  = (unsigned short*)(wsp + 46080);           // 9.44 MB
    unsigned short* Xga = Xb + (size_t)32 * NKC_ * 512;             // 9.44 MB
    unsigned short* Wc  = Xga + (size_t)576 * 16 * 512;             // 2.95 MB
    unsigned short* Wb2 = Wc + (size_t)N_ * NKC_ * 512;             // 2.95 MB
    unsigned short* Vt  = Wb2 + (size_t)576 * 5 * 64 * 8;           // 160 KB
    float* outp = (float*)d_out;

    k_prep<<<dim3(1440), dim3(256), 0, stream>>>(x, W, Xb, Xga, Wc, Wb2);
    k_sv<<<dim3(32, 5), dim3(1024), 0, stream>>>(Xb, Wc, Vt, outp, 0);
    k_ga<<<dim3(288), dim3(640), 0, stream>>>(Vt, Xga, Wb2, W, bbar, Wc, 0);
    k_sv<<<dim3(32, 5), dim3(1024), 0, stream>>>(Xb, Wc, Vt, outp, 0);
    k_ga<<<dim3(288), dim3(640), 0, stream>>>(Vt, Xga, Wb2, W, bbar, Wc, 1);
    k_sv<<<dim3(32, 5), dim3(1024), 0, stream>>>(Xb, Wc, Vt, outp, 1);
}